// Round 7
// baseline (203.252 us; speedup 1.0000x reference)
//
#include <hip/hip_runtime.h>
#include <stdint.h>

// ---------------------------------------------------------------------------
// SelfAttentiveBimodalFusion: MLP(192->16->16) -> Q(8),K(8),V(64) -> full
// N x N attention -> out (N,64).  N = 12288.  fp32 in / fp32 out.
// Validated r5-r16: absmax 9.8e-4 vs thr 2.7e-3.
//
// Ladder: r5 atomics, r9 DMA staging, r10 query-split 46us, r12 MFMA-ones
// denominator 44us, r14 counted-vmcnt NEUTRAL, r15 grid balance NEUTRAL,
// r16 zero-barrier wave-private reg staging (fragment-native vt) ~42us.
// FIVE structures land k2 at 40-47us, VALUBusy ~48% -> the bottleneck is
// the per-tile serial chain: QK-MFMA -> S -> exp issues back-to-back, so
// every tile eats the MFMA latency raw (bubble ~370cy/tile = the missing
// 52% of issue).  Loads were pipelined (A/B); the S-dependency was not.
// r17 (this): software-pipeline S across tiles:
//   - dual named S slots (SA/SB): tile i+1's QK MFMA issues BEFORE tile
//     i's exp/pack/PV (FIN) phase -> exp reads an S computed one full FIN
//     (~300cy) earlier; MFMA latency fully hidden.
//   - K-load for tile i+2 at body start (ka dead once its S computed);
//     V-frag loads right after the FIN that frees the set -> all loads
//     have >= 1 FIN-phase of lead.
//   - regs: fA/fB 40 + SA/SB 32 + acc 48 + misc ~20 = ~140 <= 170 cap at
//     launch_bounds(256,3)  (r11/r13 lessons: VGPR+AGPR total, hard cap).
// Predicted: k2 42 -> 26-30us, VALUBusy -> 60-70%.
// ---------------------------------------------------------------------------

#define NN 12288

typedef float    f32x16 __attribute__((ext_vector_type(16)));
typedef short    s16x8  __attribute__((ext_vector_type(8)));
typedef unsigned short u16;

#define MFMA_32x32x16_BF16 __builtin_amdgcn_mfma_f32_32x32x16_bf16

// ws layout (bytes)
#define OFF_QB   0u          // N*8*2 = 196608 (bf16 Q, pre-scaled)
#define OFF_VT   196608u     // 192 chunks * 9216 B (V frags 8192 + K 1024)
#define OFF_PO   2162688u    // S*N*64*2 bf16 O partials; pl follows (S*N*4)

__device__ __forceinline__ float bf2f(u16 s) {
    union { unsigned int u; float f; } c; c.u = ((unsigned int)s) << 16; return c.f;
}
__device__ __forceinline__ u16 f2bf(float f) {
    union { float f; unsigned int u; } c; c.f = f;
    return (u16)((c.u + 0x8000u) >> 16);
}
__device__ __forceinline__ unsigned int pk2(float a, float b) {
    union { float f; unsigned int u; } ca, cb; ca.f = a; cb.f = b;
    return ((ca.u + 0x8000u) >> 16) | ((cb.u + 0x8000u) & 0xffff0000u);
}
__device__ __forceinline__ unsigned int pkbf(float a, float b) {
#if __has_builtin(__builtin_amdgcn_cvt_pk_bf16_f32)
    auto r = __builtin_amdgcn_cvt_pk_bf16_f32(a, b);
    union { decltype(r) v; unsigned int u; } c; c.v = r; return c.u;
#else
    return pk2(a, b);
#endif
}
__device__ __forceinline__ f32x16 zf16() {
    f32x16 z;
#pragma unroll
    for (int i = 0; i < 16; ++i) z[i] = 0.f;
    return z;
}
__device__ __forceinline__ s16x8 zs8() {
    s16x8 z;
#pragma unroll
    for (int i = 0; i < 8; ++i) z[i] = 0;
    return z;
}

union U8 { s16x8 v; unsigned int u[4]; };
union QV { uint4 q; s16x8 v; };

// ---------------- kernel 1: detect + weights->LDS + MLP -> Qb, Vt ----------
// Vt layout per 64-key chunk (9216 B):
//   V frags: [tile t(2)][a=chanhalf(2)][b=keyhalf(2)][lane(64)][8 u16]
//     lane = h*32 + (c&31); u16 j in frag = key offset 4h + j + 4*(j>=4)
//     (+16b +32t within chunk) of channel a*32 + (c&31)  [r5 A-frag layout]
//   K block at +8192: [key(64)][8 u16]
__global__ __launch_bounds__(256) void k1_qkv(
    const void* __restrict__ xmain, const void* __restrict__ xmod,
    const void* __restrict__ we1, const void* __restrict__ we2,
    const void* __restrict__ wqp, const void* __restrict__ wkp,
    const void* __restrict__ wvp,
    u16* __restrict__ qb, u16* __restrict__ vt)
{
    __shared__ float wf[4608];
    __shared__ int   sflag;
    __shared__ float lh1[64][4][17];
    __shared__ float lh2[64][17];

    const int t = threadIdx.x;
    const int r = t >> 2;
    const int p = t & 3;
    const int row = blockIdx.x * 64 + r;

    if (t == 0) sflag = 0;
    __syncthreads();
    {
        float v = bf2f(((const u16*)xmod)[2 * t]);
        if (fabsf(v) > 16.f) atomicAdd(&sflag, 1);
    }
    __syncthreads();
    const int isf32 = (sflag > 8);

    const float SCL = 0.51006979f;       // (1/sqrt(8)) * log2(e)
    if (isf32) {
        const float* a1 = (const float*)we1; const float* a2 = (const float*)we2;
        const float* aq = (const float*)wqp; const float* ak = (const float*)wkp;
        const float* av = (const float*)wvp;
        for (int i = t; i < 4608; i += 256) {
            if      (i < 3072) wf[i] = a1[i];
            else if (i < 3328) wf[i] = a2[i - 3072];
            else if (i < 3456) wf[i] = aq[i - 3328] * SCL;
            else if (i < 3584) wf[i] = ak[i - 3456];
            else               wf[i] = av[i - 3584];
        }
    } else {
        const u16* a1 = (const u16*)we1; const u16* a2 = (const u16*)we2;
        const u16* aq = (const u16*)wqp; const u16* ak = (const u16*)wkp;
        const u16* av = (const u16*)wvp;
        for (int i = t; i < 4608; i += 256) {
            if      (i < 3072) wf[i] = bf2f(a1[i]);
            else if (i < 3328) wf[i] = bf2f(a2[i - 3072]);
            else if (i < 3456) wf[i] = bf2f(aq[i - 3328]) * SCL;
            else if (i < 3584) wf[i] = bf2f(ak[i - 3456]);
            else               wf[i] = bf2f(av[i - 3584]);
        }
    }
    __syncthreads();

    const float* __restrict__ W1 = wf;
    const float* __restrict__ W2 = wf + 3072;
    const float* __restrict__ Wq = wf + 3328;
    const float* __restrict__ Wk = wf + 3456;
    const float* __restrict__ Wv = wf + 3584;

    float h1p[16];
#pragma unroll
    for (int o = 0; o < 16; ++o) h1p[o] = 0.f;

    if (isf32) {
#pragma unroll
        for (int cc = 0; cc < 12; ++cc) {
            const int c = p + cc * 4;
            float4 xv = (c < 16)
                ? ((const float4*)xmain)[(size_t)row * 16 + c]
                : ((const float4*)xmod)[(size_t)row * 32 + (c - 16)];
            float xs[4] = {xv.x, xv.y, xv.z, xv.w};
#pragma unroll
            for (int j = 0; j < 4; ++j) {
                const float* wr = W1 + (c * 4 + j) * 16;
#pragma unroll
                for (int o = 0; o < 16; ++o) h1p[o] += xs[j] * wr[o];
            }
        }
    } else {
#pragma unroll
        for (int cc = 0; cc < 12; ++cc) {
            const int c = p + cc * 4;
            uint2 xv = (c < 16)
                ? ((const uint2*)xmain)[(size_t)row * 16 + c]
                : ((const uint2*)xmod)[(size_t)row * 32 + (c - 16)];
            float xs[4] = { bf2f((u16)(xv.x & 0xffff)), bf2f((u16)(xv.x >> 16)),
                            bf2f((u16)(xv.y & 0xffff)), bf2f((u16)(xv.y >> 16)) };
#pragma unroll
            for (int j = 0; j < 4; ++j) {
                const float* wr = W1 + (c * 4 + j) * 16;
#pragma unroll
                for (int o = 0; o < 16; ++o) h1p[o] += xs[j] * wr[o];
            }
        }
    }
#pragma unroll
    for (int o = 0; o < 16; ++o) lh1[r][p][o] = h1p[o];
    __syncthreads();

    float h1[16];
#pragma unroll
    for (int o = 0; o < 16; ++o)
        h1[o] = fmaxf(lh1[r][0][o] + lh1[r][1][o] + lh1[r][2][o] + lh1[r][3][o], 0.f);

#pragma unroll
    for (int oo = 0; oo < 4; ++oo) {
        const int o = p * 4 + oo;
        float s = 0.f;
#pragma unroll
        for (int j = 0; j < 16; ++j) s += h1[j] * W2[j * 16 + o];
        lh2[r][o] = fmaxf(s, 0.f);
    }
    __syncthreads();

    float h2[16];
#pragma unroll
    for (int j = 0; j < 16; ++j) h2[j] = lh2[r][j];

    {
        float q0 = 0.f, q1 = 0.f, k0 = 0.f, k1 = 0.f;
        const int o = 2 * p;
#pragma unroll
        for (int j = 0; j < 16; ++j) {
            q0 += h2[j] * Wq[j * 8 + o];
            q1 += h2[j] * Wq[j * 8 + o + 1];
            k0 += h2[j] * Wk[j * 8 + o];
            k1 += h2[j] * Wk[j * 8 + o + 1];
        }
        ((unsigned int*)qb)[(size_t)row * 4 + p] = pk2(q0, q1);
        // K block: chunk*2304 u32, base 2048 u32, [key&63][word p]
        ((unsigned int*)vt)[(size_t)(row >> 6) * 2304 + 2048 +
                            (row & 63) * 4 + p] = pk2(k0, k1);
    }

    // V store into fragment-native layout (see header comment)
    {
        const int ch = row >> 6, tI = (row >> 5) & 1, kk = row & 31;
        const int b   = kk >> 4, kk4 = kk & 15;
        const int hh  = (kk4 >> 2) & 1;
        const int jj  = (kk4 & 3) + 4 * (kk4 >> 3);
        const size_t cbase = (size_t)ch * 4608 + (size_t)(tI * 4 + b) * 512
                           + hh * 256 + jj;
#pragma unroll
        for (int c16 = 0; c16 < 16; ++c16) {
            const int c = p * 16 + c16;
            float v = 0.f;
#pragma unroll
            for (int j = 0; j < 16; ++j) v += h2[j] * Wv[j * 64 + c];
            vt[cbase + (size_t)(c >> 5) * 1024 + (c & 31) * 8] = f2bf(v);
        }
    }
}

// --------------------------- kernel 2: attention partials -------------------
// grid = 96 q-blocks * S=8 key-splits = 768 blocks = exactly 3 blocks/CU,
// one balanced round.  4 independent waves / block, zero barriers.
// Software-pipelined: dual S slots decouple QK-MFMA latency from the exp
// burst; K loads lead by ~1 FIN phase, V-frag loads by ~1 iteration.

__global__ __launch_bounds__(256, 3) void k2_attn(
    const u16* __restrict__ qb, const u16* __restrict__ vt,
    u16* __restrict__ po, float* __restrict__ pl,
    int nsplit, int ntile)
{
    __shared__ float sf[4][2178];            // per-wave private scratch

    const int tid  = threadIdx.x;
    const int lane = tid & 63;
    const int half = lane >> 5;
    const int l31  = lane & 31;
    const int w    = tid >> 6;               // wave 0..3
    const int qB   = (blockIdx.x % 96) * 128;
    const int sp   = blockIdx.x / 96;
    const int myq  = qB + 32 * w;
    const int key_start = sp * (NN / nsplit);
    const char* vbase = (const char*)vt + (size_t)(key_start >> 6) * 9216;

    const f32x16 Z = zf16();
    s16x8 qf = zs8();
    if (!half) qf = *(const s16x8*)(qb + (size_t)(myq + l31) * 8);

    s16x8 ones;
#pragma unroll
    for (int i = 0; i < 8; ++i) ones[i] = (short)0x3F80;   // bf16 1.0

    f32x16 acc0 = Z, acc1 = Z, accl = Z;

    QV kaA, f00A, f10A, f01A, f11A;
    QV kaB, f00B, f10B, f01B, f11B;

    // K fragment load for tile gt (1 dwordx4)
#define LDK(gt, ka) do {                                                      \
    (ka).q = *(const uint4*)(vbase + (size_t)((gt) >> 1) * 9216 + 8192        \
                             + ((gt) & 1) * 512 + l31 * 16);                  \
} while (0)

    // V fragment loads for tile gt (4 coalesced dwordx4)
#define LDV(gt, f00, f10, f01, f11) do {                                      \
    const char* cb_ = vbase + (size_t)((gt) >> 1) * 9216 + ((gt) & 1) * 4096; \
    (f00).q = *(const uint4*)(cb_ +        lane * 16);                        \
    (f01).q = *(const uint4*)(cb_ + 1024 + lane * 16);                        \
    (f10).q = *(const uint4*)(cb_ + 2048 + lane * 16);                        \
    (f11).q = *(const uint4*)(cb_ + 3072 + lane * 16);                        \
} while (0)

    // finish one 32-key tile from its precomputed S: exp -> pack -> l-sum
    // MFMA -> 4 PV MFMAs  (r5-validated relabeling)
#define FIN(S_, f00, f10, f01, f11) do {                                      \
    float pr_[16];                                                            \
    _Pragma("unroll")                                                         \
    for (int r_ = 0; r_ < 16; ++r_) pr_[r_] = __builtin_amdgcn_exp2f((S_)[r_]);\
    U8 p0_, p1_;                                                              \
    _Pragma("unroll")                                                         \
    for (int i_ = 0; i_ < 4; ++i_) {                                          \
        p0_.u[i_] = pkbf(pr_[2 * i_],     pr_[2 * i_ + 1]);                   \
        p1_.u[i_] = pkbf(pr_[8 + 2 * i_], pr_[8 + 2 * i_ + 1]);               \
    }                                                                         \
    accl = MFMA_32x32x16_BF16(ones, p0_.v, accl, 0, 0, 0);                    \
    accl = MFMA_32x32x16_BF16(ones, p1_.v, accl, 0, 0, 0);                    \
    acc0 = MFMA_32x32x16_BF16((f00).v, p0_.v, acc0, 0, 0, 0);                 \
    acc1 = MFMA_32x32x16_BF16((f10).v, p0_.v, acc1, 0, 0, 0);                 \
    acc0 = MFMA_32x32x16_BF16((f01).v, p1_.v, acc0, 0, 0, 0);                 \
    acc1 = MFMA_32x32x16_BF16((f11).v, p1_.v, acc1, 0, 0, 0);                 \
} while (0)

    // prologue: tiles 0,1 fully loaded; S(0) computed (stalls once, ok)
    LDV(0, f00A, f10A, f01A, f11A);
    LDK(0, kaA);
    LDV(1, f00B, f10B, f01B, f11B);
    LDK(1, kaB);
    f32x16 SA = MFMA_32x32x16_BF16(kaA.v, qf, Z, 0, 0, 0);
    f32x16 SB;

    int gt = 0;
    for (; gt + 2 < ntile; gt += 2) {
        LDK(gt + 2, kaA);                    // kaA dead: S(gt) already in SA
        SB = MFMA_32x32x16_BF16(kaB.v, qf, Z, 0, 0, 0);   // S(gt+1), early
        FIN(SA, f00A, f10A, f01A, f11A);     // finish tile gt (frees A frags)
        LDV(gt + 2, f00A, f10A, f01A, f11A);
        LDK(gt + 3, kaB);                    // kaB dead: S(gt+1) in SB
        SA = MFMA_32x32x16_BF16(kaA.v, qf, Z, 0, 0, 0);   // S(gt+2), early
        FIN(SB, f00B, f10B, f01B, f11B);     // finish tile gt+1
        LDV(gt + 3, f00B, f10B, f01B, f11B);
    }
    // tail: tiles gt, gt+1 (SA holds S(gt); B fully loaded)
    SB = MFMA_32x32x16_BF16(kaB.v, qf, Z, 0, 0, 0);
    FIN(SA, f00A, f10A, f01A, f11A);
    FIN(SB, f00B, f10B, f01B, f11B);

#undef LDK
#undef LDV
#undef FIN

    // denominator: all accl rows identical = full 64-lane key-sum per query
    const float ls = accl[0];

    // ---- epilogue: per-wave PRIVATE transpose scratch, zero barriers ------
    float* sfw = &sf[w][0];
#pragma unroll
    for (int r = 0; r < 16; ++r) {
        const int c = (r & 3) + 8 * (r >> 2) + 4 * half;
        sfw[c * 33 + l31]        = acc0[r];
        sfw[(32 + c) * 33 + l31] = acc1[r];
    }
    if (lane < 32) sfw[2112 + l31] = ls;

    u16* poS = po + (size_t)sp * (NN * 64);
    const int lq  = lane >> 1;               // query 0..31 within wave
    const int cb0 = (lane & 1) * 32;         // channel base 0 or 32
    unsigned int u[16];
#pragma unroll
    for (int i = 0; i < 16; ++i)
        u[i] = pkbf(sfw[(cb0 + 2 * i) * 33 + lq],
                    sfw[(cb0 + 2 * i + 1) * 33 + lq]);
    u16* dst = poS + (size_t)(myq + lq) * 64 + cb0;
    *(uint4*)(dst)      = make_uint4(u[0],  u[1],  u[2],  u[3]);
    *(uint4*)(dst + 8)  = make_uint4(u[4],  u[5],  u[6],  u[7]);
    *(uint4*)(dst + 16) = make_uint4(u[8],  u[9],  u[10], u[11]);
    *(uint4*)(dst + 24) = make_uint4(u[12], u[13], u[14], u[15]);
    if (lane < 32)
        pl[(size_t)sp * NN + myq + l31] = sfw[2112 + l31];
}

// --------------------------- kernel 3: reduce splits + normalize ------------
__global__ __launch_bounds__(256) void k3_norm(
    const u16* __restrict__ po, const float* __restrict__ pl,
    float4* __restrict__ out, int nsplit)
{
    const int i = blockIdx.x * 256 + threadIdx.x;   // 196608 float4 outputs
    const int row = i >> 4;
    const int c0 = (i & 15) * 4;
    float l = 0.f;
    float o0 = 0.f, o1 = 0.f, o2 = 0.f, o3 = 0.f;
    for (int s = 0; s < nsplit; ++s) {
        l += pl[(size_t)s * NN + row];
        uint2 p = *(const uint2*)(po + (size_t)s * (NN * 64) +
                                  (size_t)row * 64 + c0);
        o0 += bf2f((u16)(p.x & 0xffff)); o1 += bf2f((u16)(p.x >> 16));
        o2 += bf2f((u16)(p.y & 0xffff)); o3 += bf2f((u16)(p.y >> 16));
    }
    const float rl = 1.0f / l;
    out[i] = make_float4(o0 * rl, o1 * rl, o2 * rl, o3 * rl);
}

// ---------------------------------------------------------------------------
extern "C" void kernel_launch(void* const* d_in, const int* in_sizes, int n_in,
                              void* d_out, int out_size, void* d_ws, size_t ws_size,
                              hipStream_t stream)
{
    const void* xmain = d_in[0];
    const void* xmod  = d_in[1];
    // d_in[2] = xyz (unused by the reference)
    const void* we1   = d_in[3];
    const void* we2   = d_in[4];
    const void* wq    = d_in[5];
    const void* wk    = d_in[6];
    const void* wv    = d_in[7];

    char* ws = (char*)d_ws;
    u16*   qb   = (u16*)  (ws + OFF_QB);
    u16*   vt   = (u16*)  (ws + OFF_VT);

    // S = 8: grid 768 = exactly 3 blocks/CU, one balanced round, minimal
    // partial traffic.  Fallback halving only if ws is unexpectedly small.
    int S = 8;
    while (S > 1) {
        size_t need = (size_t)OFF_PO + (size_t)S * (NN * 64 * 2) +
                      (size_t)S * (NN * 4);
        if (ws_size >= need) break;
        S >>= 1;
    }
    u16*   po = (u16*)(ws + OFF_PO);
    float* pl = (float*)(ws + OFF_PO + (size_t)S * (NN * 64 * 2));
    const int ntile = NN / (32 * S);

    k1_qkv<<<192, 256, 0, stream>>>(xmain, xmod, we1, we2, wq, wk, wv,
                                    qb, vt);
    k2_attn<<<96 * S, 256, 0, stream>>>(qb, vt, po, pl, S, ntile);
    k3_norm<<<768, 256, 0, stream>>>(po, pl, (float4*)d_out, S);
}

// Round 8
// 135.065 us; speedup vs baseline: 1.5048x; 1.5048x over previous
//
#include <hip/hip_runtime.h>
#include <stdint.h>

// ---------------------------------------------------------------------------
// SelfAttentiveBimodalFusion: MLP(192->16->16) -> Q(8),K(8),V(64) -> full
// N x N attention -> out (N,64).  N = 12288.  fp32 in / fp32 out.
// Validated r5-r16: absmax 9.8e-4 vs thr 2.7e-3.
//
// Ladder: r10 46us, r12 44us, r14/r15 NEUTRAL, r16 zero-barrier wave-
// private reg staging -> k2 ~40-42us, total 127.1 (best).
// r11 FAILED spill; r13 FAILED occupancy bracket; r17 FAILED spill again:
// dual-S + dual V-frag sets peak at ~200 live regs > 170 cap -> scratch
// (WRITE_SIZE 118MB, k2 120us).  LESSON: count liveness at the worst
// instruction, not by summing named buffers.
// r18 (this): same S-pipeline hypothesis, register-lean:
//   - V/K staged through PER-WAVE-PRIVATE LDS double buffer via
//     global_load_lds (zero VGPR cost); FIN reads fragments ds_read_b128
//     just-in-time (<=16 transient regs).  vt relaid: one 4608B record
//     per 32-key tile (V frags 4096 + K 512) = exactly 5 DMA/tile/wave.
//   - ZERO barriers: same-wave vmcnt/lgkmcnt ordering only;
//     sched_barrier(0) pins the waits.  Dual named S slots: S(i+1)'s QK
//     MFMA issues before FIN(i)'s exp burst -> MFMA latency hidden.
//   - peak liveness ~155 <= 170 cap at launch_bounds(256,3).
//   - LDS 36864B/block = staging (2x4608B/wave) U epilogue scratch.
// Predicted: k2 -> 26-32us if S-chain theory right; if ~40 unchanged,
// pivot to trans/VALU execute floor.
// ---------------------------------------------------------------------------

#define NN 12288

typedef float    f32x16 __attribute__((ext_vector_type(16)));
typedef short    s16x8  __attribute__((ext_vector_type(8)));
typedef unsigned short u16;

#define MFMA_32x32x16_BF16 __builtin_amdgcn_mfma_f32_32x32x16_bf16

// ws layout (bytes)
#define OFF_QB   0u          // N*8*2 = 196608 (bf16 Q, pre-scaled)
#define OFF_VT   196608u     // 384 tiles * 4608 B (V frags 4096 + K 512)
#define OFF_PO   2162688u    // S*N*64*2 bf16 O partials; pl follows (S*N*4)

// s_waitcnt imm encodings (gfx9 style): vm[3:0]|exp[6:4]|lgkm[11:8]|vmhi[15:14]
#define WC_VM(n)   (0x0F70 | (n))    // vmcnt(n), exp/lgkm nowait
#define WC_LGKM0   (0xC07F)          // lgkmcnt(0), vm/exp nowait

typedef __attribute__((address_space(3))) void lds_void_t;
typedef const __attribute__((address_space(1))) void gbl_void_t;
__device__ __forceinline__ void gld16(const void* g, void* l) {
    __builtin_amdgcn_global_load_lds((gbl_void_t*)g, (lds_void_t*)l, 16, 0, 0);
}

__device__ __forceinline__ float bf2f(u16 s) {
    union { unsigned int u; float f; } c; c.u = ((unsigned int)s) << 16; return c.f;
}
__device__ __forceinline__ u16 f2bf(float f) {
    union { float f; unsigned int u; } c; c.f = f;
    return (u16)((c.u + 0x8000u) >> 16);
}
__device__ __forceinline__ unsigned int pk2(float a, float b) {
    union { float f; unsigned int u; } ca, cb; ca.f = a; cb.f = b;
    return ((ca.u + 0x8000u) >> 16) | ((cb.u + 0x8000u) & 0xffff0000u);
}
__device__ __forceinline__ unsigned int pkbf(float a, float b) {
#if __has_builtin(__builtin_amdgcn_cvt_pk_bf16_f32)
    auto r = __builtin_amdgcn_cvt_pk_bf16_f32(a, b);
    union { decltype(r) v; unsigned int u; } c; c.v = r; return c.u;
#else
    return pk2(a, b);
#endif
}
__device__ __forceinline__ f32x16 zf16() {
    f32x16 z;
#pragma unroll
    for (int i = 0; i < 16; ++i) z[i] = 0.f;
    return z;
}
__device__ __forceinline__ s16x8 zs8() {
    s16x8 z;
#pragma unroll
    for (int i = 0; i < 8; ++i) z[i] = 0;
    return z;
}

union U8 { s16x8 v; unsigned int u[4]; };
union QV { uint4 q; s16x8 v; };

// ---------------- kernel 1: detect + weights->LDS + MLP -> Qb, Vt ----------
// Vt layout per 32-key TILE (4608 B):
//   V frags (4096 B): [a=chanhalf(2)][b=keyhalf(2)][lane(64)][8 u16]
//     lane = hh*32 + (c&31); u16 j = key offset within b-half (r5 A-frag)
//   K frag at +4096 (512 B): [key(32)][8 u16]
__global__ __launch_bounds__(256) void k1_qkv(
    const void* __restrict__ xmain, const void* __restrict__ xmod,
    const void* __restrict__ we1, const void* __restrict__ we2,
    const void* __restrict__ wqp, const void* __restrict__ wkp,
    const void* __restrict__ wvp,
    u16* __restrict__ qb, u16* __restrict__ vt)
{
    __shared__ float wf[4608];
    __shared__ int   sflag;
    __shared__ float lh1[64][4][17];
    __shared__ float lh2[64][17];

    const int t = threadIdx.x;
    const int r = t >> 2;
    const int p = t & 3;
    const int row = blockIdx.x * 64 + r;

    if (t == 0) sflag = 0;
    __syncthreads();
    {
        float v = bf2f(((const u16*)xmod)[2 * t]);
        if (fabsf(v) > 16.f) atomicAdd(&sflag, 1);
    }
    __syncthreads();
    const int isf32 = (sflag > 8);

    const float SCL = 0.51006979f;       // (1/sqrt(8)) * log2(e)
    if (isf32) {
        const float* a1 = (const float*)we1; const float* a2 = (const float*)we2;
        const float* aq = (const float*)wqp; const float* ak = (const float*)wkp;
        const float* av = (const float*)wvp;
        for (int i = t; i < 4608; i += 256) {
            if      (i < 3072) wf[i] = a1[i];
            else if (i < 3328) wf[i] = a2[i - 3072];
            else if (i < 3456) wf[i] = aq[i - 3328] * SCL;
            else if (i < 3584) wf[i] = ak[i - 3456];
            else               wf[i] = av[i - 3584];
        }
    } else {
        const u16* a1 = (const u16*)we1; const u16* a2 = (const u16*)we2;
        const u16* aq = (const u16*)wqp; const u16* ak = (const u16*)wkp;
        const u16* av = (const u16*)wvp;
        for (int i = t; i < 4608; i += 256) {
            if      (i < 3072) wf[i] = bf2f(a1[i]);
            else if (i < 3328) wf[i] = bf2f(a2[i - 3072]);
            else if (i < 3456) wf[i] = bf2f(aq[i - 3328]) * SCL;
            else if (i < 3584) wf[i] = bf2f(ak[i - 3456]);
            else               wf[i] = bf2f(av[i - 3584]);
        }
    }
    __syncthreads();

    const float* __restrict__ W1 = wf;
    const float* __restrict__ W2 = wf + 3072;
    const float* __restrict__ Wq = wf + 3328;
    const float* __restrict__ Wk = wf + 3456;
    const float* __restrict__ Wv = wf + 3584;

    float h1p[16];
#pragma unroll
    for (int o = 0; o < 16; ++o) h1p[o] = 0.f;

    if (isf32) {
#pragma unroll
        for (int cc = 0; cc < 12; ++cc) {
            const int c = p + cc * 4;
            float4 xv = (c < 16)
                ? ((const float4*)xmain)[(size_t)row * 16 + c]
                : ((const float4*)xmod)[(size_t)row * 32 + (c - 16)];
            float xs[4] = {xv.x, xv.y, xv.z, xv.w};
#pragma unroll
            for (int j = 0; j < 4; ++j) {
                const float* wr = W1 + (c * 4 + j) * 16;
#pragma unroll
                for (int o = 0; o < 16; ++o) h1p[o] += xs[j] * wr[o];
            }
        }
    } else {
#pragma unroll
        for (int cc = 0; cc < 12; ++cc) {
            const int c = p + cc * 4;
            uint2 xv = (c < 16)
                ? ((const uint2*)xmain)[(size_t)row * 16 + c]
                : ((const uint2*)xmod)[(size_t)row * 32 + (c - 16)];
            float xs[4] = { bf2f((u16)(xv.x & 0xffff)), bf2f((u16)(xv.x >> 16)),
                            bf2f((u16)(xv.y & 0xffff)), bf2f((u16)(xv.y >> 16)) };
#pragma unroll
            for (int j = 0; j < 4; ++j) {
                const float* wr = W1 + (c * 4 + j) * 16;
#pragma unroll
                for (int o = 0; o < 16; ++o) h1p[o] += xs[j] * wr[o];
            }
        }
    }
#pragma unroll
    for (int o = 0; o < 16; ++o) lh1[r][p][o] = h1p[o];
    __syncthreads();

    float h1[16];
#pragma unroll
    for (int o = 0; o < 16; ++o)
        h1[o] = fmaxf(lh1[r][0][o] + lh1[r][1][o] + lh1[r][2][o] + lh1[r][3][o], 0.f);

#pragma unroll
    for (int oo = 0; oo < 4; ++oo) {
        const int o = p * 4 + oo;
        float s = 0.f;
#pragma unroll
        for (int j = 0; j < 16; ++j) s += h1[j] * W2[j * 16 + o];
        lh2[r][o] = fmaxf(s, 0.f);
    }
    __syncthreads();

    float h2[16];
#pragma unroll
    for (int j = 0; j < 16; ++j) h2[j] = lh2[r][j];

    const int tt = row >> 5, kk = row & 31;   // global tile, key-in-tile
    {
        float q0 = 0.f, q1 = 0.f, k0 = 0.f, k1 = 0.f;
        const int o = 2 * p;
#pragma unroll
        for (int j = 0; j < 16; ++j) {
            q0 += h2[j] * Wq[j * 8 + o];
            q1 += h2[j] * Wq[j * 8 + o + 1];
            k0 += h2[j] * Wk[j * 8 + o];
            k1 += h2[j] * Wk[j * 8 + o + 1];
        }
        ((unsigned int*)qb)[(size_t)row * 4 + p] = pk2(q0, q1);
        // K frag: u32 units: tile*1152 + 1024 + key*4 + word
        ((unsigned int*)vt)[(size_t)tt * 1152 + 1024 + kk * 4 + p] = pk2(k0, k1);
    }

    // V store into per-tile fragment-native layout
    {
        const int b   = kk >> 4, kk4 = kk & 15;
        const int hh  = (kk4 >> 2) & 1;
        const int jj  = (kk4 & 3) + 4 * (kk4 >> 3);
        const size_t cbase = (size_t)tt * 2304 + b * 512 + hh * 256 + jj;
#pragma unroll
        for (int c16 = 0; c16 < 16; ++c16) {
            const int c = p * 16 + c16;
            float v = 0.f;
#pragma unroll
            for (int j = 0; j < 16; ++j) v += h2[j] * Wv[j * 64 + c];
            vt[cbase + (size_t)(c >> 5) * 1024 + (c & 31) * 8] = f2bf(v);
        }
    }
}

// --------------------------- kernel 2: attention partials -------------------
// grid = 96 q-blocks * S=8 = 768 blocks; 4 independent waves / block, ZERO
// barriers.  Per-wave-private LDS double buffer (2 x 4608B), 5 DMA/tile,
// counted vmcnt, dual-S software pipeline.  launch_bounds(256,3): cap 170,
// peak liveness ~155 (r11/r17 lessons: audit at worst instruction).

__global__ __launch_bounds__(256, 3) void k2_attn(
    const u16* __restrict__ qb, const u16* __restrict__ vt,
    u16* __restrict__ po, float* __restrict__ pl,
    int nsplit, int ntile)
{
    __shared__ uint4 smem[2304];             // 36864 B = 4 waves x 9216 B

    const int tid  = threadIdx.x;
    const int lane = tid & 63;
    const int half = lane >> 5;
    const int l31  = lane & 31;
    const int w    = tid >> 6;               // wave 0..3
    const int qB   = (blockIdx.x % 96) * 128;
    const int sp   = blockIdx.x / 96;
    const int myq  = qB + 32 * w;
    const int tile0 = sp * (NN / nsplit) / 32;

    uint4* lb0 = &smem[w * 576];             // this wave's buffer 0 (4608 B)
    uint4* lb1 = lb0 + 288;                  // buffer 1

    const f32x16 Z = zf16();
    s16x8 qf = zs8();
    if (!half) qf = *(const s16x8*)(qb + (size_t)(myq + l31) * 8);

    s16x8 ones;
#pragma unroll
    for (int i = 0; i < 8; ++i) ones[i] = (short)0x3F80;   // bf16 1.0

    f32x16 acc0 = Z, acc1 = Z, accl = Z;

    // stage tile t (global index) into this wave's LDS buffer: 5 DMA ops
#define STAGE(t, lbase) do {                                                  \
    const char* g_ = (const char*)vt + (size_t)(t) * 4608 + lane * 16;        \
    char* l_ = (char*)(lbase);                                                \
    gld16(g_, l_);                                                            \
    gld16(g_ + 1024, l_ + 1024);                                              \
    gld16(g_ + 2048, l_ + 2048);                                              \
    gld16(g_ + 3072, l_ + 3072);                                              \
    if (lane < 32) gld16(g_ + 4096, l_ + 4096);                               \
} while (0)

    // K fragment from LDS buffer (tile resident)
#define LDSK(lbase, ka) do {                                                  \
    (ka).q = *((const uint4*)(lbase) + 256 + l31);                            \
} while (0)

    // finish one tile from its precomputed S; V frags ds_read just-in-time
#define FIN(S_, lbase) do {                                                   \
    float pr_[16];                                                            \
    _Pragma("unroll")                                                         \
    for (int r_ = 0; r_ < 16; ++r_) pr_[r_] = __builtin_amdgcn_exp2f((S_)[r_]);\
    U8 p0_, p1_;                                                              \
    _Pragma("unroll")                                                         \
    for (int i_ = 0; i_ < 4; ++i_) {                                          \
        p0_.u[i_] = pkbf(pr_[2 * i_],     pr_[2 * i_ + 1]);                   \
        p1_.u[i_] = pkbf(pr_[8 + 2 * i_], pr_[8 + 2 * i_ + 1]);               \
    }                                                                         \
    accl = MFMA_32x32x16_BF16(ones, p0_.v, accl, 0, 0, 0);                    \
    accl = MFMA_32x32x16_BF16(ones, p1_.v, accl, 0, 0, 0);                    \
    QV f_;                                                                    \
    f_.q = *((const uint4*)(lbase) + lane);                                   \
    acc0 = MFMA_32x32x16_BF16(f_.v, p0_.v, acc0, 0, 0, 0);                    \
    f_.q = *((const uint4*)(lbase) + 128 + lane);                             \
    acc1 = MFMA_32x32x16_BF16(f_.v, p0_.v, acc1, 0, 0, 0);                    \
    f_.q = *((const uint4*)(lbase) + 64 + lane);                              \
    acc0 = MFMA_32x32x16_BF16(f_.v, p1_.v, acc0, 0, 0, 0);                    \
    f_.q = *((const uint4*)(lbase) + 192 + lane);                             \
    acc1 = MFMA_32x32x16_BF16(f_.v, p1_.v, acc1, 0, 0, 0);                    \
} while (0)

#define WAIT_VM(n) do {                                                       \
    __builtin_amdgcn_s_waitcnt(WC_VM(n));                                     \
    __builtin_amdgcn_sched_barrier(0);                                        \
} while (0)
#define WAIT_LGKM() do {                                                      \
    __builtin_amdgcn_s_waitcnt(WC_LGKM0);                                     \
    __builtin_amdgcn_sched_barrier(0);                                        \
} while (0)

    // prologue: stage tiles 0,1; S(0)
    STAGE(tile0 + 0, lb0);
    STAGE(tile0 + 1, lb1);
    WAIT_VM(5);                              // tile 0 resident
    QV ka;
    LDSK(lb0, ka);
    f32x16 SA = MFMA_32x32x16_BF16(ka.v, qf, Z, 0, 0, 0);
    f32x16 SB;

    int gt = 0;
    for (; gt + 2 < ntile; gt += 2) {
        WAIT_VM(0);                          // tile gt+1 resident (1-FIN lead)
        LDSK(lb1, ka);
        SB = MFMA_32x32x16_BF16(ka.v, qf, Z, 0, 0, 0);   // S(gt+1) early
        FIN(SA, lb0);                        // tile gt; frees lb0
        WAIT_LGKM();                         // lb0 reads landed
        STAGE(tile0 + gt + 2, lb0);
        WAIT_VM(0);                          // tile gt+2 resident (1-FIN lead)
        LDSK(lb0, ka);
        SA = MFMA_32x32x16_BF16(ka.v, qf, Z, 0, 0, 0);   // S(gt+2) early
        FIN(SB, lb1);                        // tile gt+1; frees lb1
        WAIT_LGKM();
        if (gt + 3 < ntile) STAGE(tile0 + gt + 3, lb1);
    }
    // tail: tiles gt, gt+1 (ntile even; both staged)
    WAIT_VM(0);
    LDSK(lb1, ka);
    SB = MFMA_32x32x16_BF16(ka.v, qf, Z, 0, 0, 0);
    FIN(SA, lb0);
    FIN(SB, lb1);

#undef STAGE
#undef LDSK
#undef FIN
#undef WAIT_VM
#undef WAIT_LGKM

    // denominator: all accl rows identical = full 64-lane key-sum per query
    const float ls = accl[0];

    // ---- epilogue: per-wave PRIVATE transpose scratch (aliases staging) ---
    WAIT_LGKM_EPI:;
    __builtin_amdgcn_s_waitcnt(WC_LGKM0);    // last FIN's ds_reads done
    float* sfw = (float*)&smem[w * 576];     // 9216 B >= 2178 floats
#pragma unroll
    for (int r = 0; r < 16; ++r) {
        const int c = (r & 3) + 8 * (r >> 2) + 4 * half;
        sfw[c * 33 + l31]        = acc0[r];
        sfw[(32 + c) * 33 + l31] = acc1[r];
    }
    if (lane < 32) sfw[2112 + l31] = ls;

    u16* poS = po + (size_t)sp * (NN * 64);
    const int lq  = lane >> 1;               // query 0..31 within wave
    const int cb0 = (lane & 1) * 32;         // channel base 0 or 32
    unsigned int u[16];
#pragma unroll
    for (int i = 0; i < 16; ++i)
        u[i] = pkbf(sfw[(cb0 + 2 * i) * 33 + lq],
                    sfw[(cb0 + 2 * i + 1) * 33 + lq]);
    u16* dst = poS + (size_t)(myq + lq) * 64 + cb0;
    *(uint4*)(dst)      = make_uint4(u[0],  u[1],  u[2],  u[3]);
    *(uint4*)(dst + 8)  = make_uint4(u[4],  u[5],  u[6],  u[7]);
    *(uint4*)(dst + 16) = make_uint4(u[8],  u[9],  u[10], u[11]);
    *(uint4*)(dst + 24) = make_uint4(u[12], u[13], u[14], u[15]);
    if (lane < 32)
        pl[(size_t)sp * NN + myq + l31] = sfw[2112 + l31];
}

// --------------------------- kernel 3: reduce splits + normalize ------------
__global__ __launch_bounds__(256) void k3_norm(
    const u16* __restrict__ po, const float* __restrict__ pl,
    float4* __restrict__ out, int nsplit)
{
    const int i = blockIdx.x * 256 + threadIdx.x;   // 196608 float4 outputs
    const int row = i >> 4;
    const int c0 = (i & 15) * 4;
    float l = 0.f;
    float o0 = 0.f, o1 = 0.f, o2 = 0.f, o3 = 0.f;
    for (int s = 0; s < nsplit; ++s) {
        l += pl[(size_t)s * NN + row];
        uint2 p = *(const uint2*)(po + (size_t)s * (NN * 64) +
                                  (size_t)row * 64 + c0);
        o0 += bf2f((u16)(p.x & 0xffff)); o1 += bf2f((u16)(p.x >> 16));
        o2 += bf2f((u16)(p.y & 0xffff)); o3 += bf2f((u16)(p.y >> 16));
    }
    const float rl = 1.0f / l;
    out[i] = make_float4(o0 * rl, o1 * rl, o2 * rl, o3 * rl);
}

// ---------------------------------------------------------------------------
extern "C" void kernel_launch(void* const* d_in, const int* in_sizes, int n_in,
                              void* d_out, int out_size, void* d_ws, size_t ws_size,
                              hipStream_t stream)
{
    const void* xmain = d_in[0];
    const void* xmod  = d_in[1];
    // d_in[2] = xyz (unused by the reference)
    const void* we1   = d_in[3];
    const void* we2   = d_in[4];
    const void* wq    = d_in[5];
    const void* wk    = d_in[6];
    const void* wv    = d_in[7];

    char* ws = (char*)d_ws;
    u16*   qb   = (u16*)  (ws + OFF_QB);
    u16*   vt   = (u16*)  (ws + OFF_VT);

    // S = 8: grid 768 = 3 blocks/CU, one balanced round, minimal partials.
    int S = 8;
    while (S > 1) {
        size_t need = (size_t)OFF_PO + (size_t)S * (NN * 64 * 2) +
                      (size_t)S * (NN * 4);
        if (ws_size >= need) break;
        S >>= 1;
    }
    u16*   po = (u16*)(ws + OFF_PO);
    float* pl = (float*)(ws + OFF_PO + (size_t)S * (NN * 64 * 2));
    const int ntile = NN / (32 * S);

    k1_qkv<<<192, 256, 0, stream>>>(xmain, xmod, we1, we2, wq, wk, wv,
                                    qb, vt);
    k2_attn<<<96 * S, 256, 0, stream>>>(qb, vt, po, pl, S, ntile);
    k3_norm<<<768, 256, 0, stream>>>(po, pl, (float4*)d_out, S);
}

// Round 9
// 132.619 us; speedup vs baseline: 1.5326x; 1.0184x over previous
//
#include <hip/hip_runtime.h>
#include <stdint.h>

// ---------------------------------------------------------------------------
// SelfAttentiveBimodalFusion: MLP(192->16->16) -> Q(8),K(8),V(64) -> full
// N x N attention -> out (N,64).  N = 12288.  fp32 in / fp32 out.
// Validated r5-r18: absmax 9.8e-4 vs thr 2.7e-3.
//
// Ladder: r10 46us, r12 44us, r16 zero-barrier reg staging 42us / total
// 127.1 (best).  r11/r17 FAILED (spill: audit liveness at worst instr);
// r13 FAILED (occupancy bracket); r14/r15 NEUTRAL; r18 FAILED: both
// WAIT_VM(0)s sat immediately after the STAGE they waited on -> zero lead,
// raw DMA latency every tile, k2 53us at VALUBusy 38%.
// r19 (this): same dual-S + LDS-V pipeline, with REAL leads:
//   - K in a register double buffer (16B/lane, r16-validated path) so the
//     LDS pipeline carries V only (4 DMA/tile); K(i+1) is loaded one pair
//     ahead, S(i+1) computed one FIN ahead, V(i) staged ~2 halves ahead.
//   - vmcnt ledger (5 vm-ops/half): at each WAIT_VM(6) the required
//     V-stage is exactly the 7th-oldest op; tail pairs peel at 4/0.
//     K-load placement alternates (H1: right after its consumer QK;
//     H2: after the SV) so compiler K-waits never drain young V-stages.
//   - peak liveness ~156 <= 170 cap at launch_bounds(256,3); LDS
//     4 x 8704B = 34816/block -> 3 blocks/CU, 768-block grid = 1 round.
// Predicted: k2 -> 25-32us; if ~40 with clean counters, latency theory is
// exhausted -> pivot to exp-count/fusion.
// ---------------------------------------------------------------------------

#define NN 12288

typedef float    f32x16 __attribute__((ext_vector_type(16)));
typedef short    s16x8  __attribute__((ext_vector_type(8)));
typedef unsigned short u16;

#define MFMA_32x32x16_BF16 __builtin_amdgcn_mfma_f32_32x32x16_bf16

// ws layout (bytes)
#define OFF_QB   0u          // N*8*2 = 196608 (bf16 Q, pre-scaled)
#define OFF_KB   196608u     // N*8*2 = 196608 (bf16 K, 16B/key)
#define OFF_VT   393216u     // 384 tiles * 4096 B V fragments
#define OFF_PO   2162688u    // S*N*64*2 bf16 O partials; pl follows (S*N*4)

// s_waitcnt imm encodings: vm[3:0]|exp[6:4]|lgkm[11:8]|vmhi[15:14]
#define WC_VM(n)   (0x0F70 | (n))    // vmcnt(n), exp/lgkm nowait
#define WC_LGKM0   (0xC07F)          // lgkmcnt(0), vm/exp nowait

typedef __attribute__((address_space(3))) void lds_void_t;
typedef const __attribute__((address_space(1))) void gbl_void_t;
__device__ __forceinline__ void gld16(const void* g, void* l) {
    __builtin_amdgcn_global_load_lds((gbl_void_t*)g, (lds_void_t*)l, 16, 0, 0);
}

__device__ __forceinline__ float bf2f(u16 s) {
    union { unsigned int u; float f; } c; c.u = ((unsigned int)s) << 16; return c.f;
}
__device__ __forceinline__ u16 f2bf(float f) {
    union { float f; unsigned int u; } c; c.f = f;
    return (u16)((c.u + 0x8000u) >> 16);
}
__device__ __forceinline__ unsigned int pk2(float a, float b) {
    union { float f; unsigned int u; } ca, cb; ca.f = a; cb.f = b;
    return ((ca.u + 0x8000u) >> 16) | ((cb.u + 0x8000u) & 0xffff0000u);
}
__device__ __forceinline__ unsigned int pkbf(float a, float b) {
#if __has_builtin(__builtin_amdgcn_cvt_pk_bf16_f32)
    auto r = __builtin_amdgcn_cvt_pk_bf16_f32(a, b);
    union { decltype(r) v; unsigned int u; } c; c.v = r; return c.u;
#else
    return pk2(a, b);
#endif
}
__device__ __forceinline__ f32x16 zf16() {
    f32x16 z;
#pragma unroll
    for (int i = 0; i < 16; ++i) z[i] = 0.f;
    return z;
}
__device__ __forceinline__ s16x8 zs8() {
    s16x8 z;
#pragma unroll
    for (int i = 0; i < 8; ++i) z[i] = 0;
    return z;
}

union U8 { s16x8 v; unsigned int u[4]; };
union QV { uint4 q; s16x8 v; };

// ---------------- kernel 1: detect + weights->LDS + MLP -> Qb, Kb, Vt ------
// Vt layout per 32-key TILE (4096 B): [a=chanhalf(2)][b=keyhalf(2)]
//   [lane(64)][8 u16]  (r5-validated A-fragment order)
// Kb: [key][8 u16] (16 B per key)
__global__ __launch_bounds__(256) void k1_qkv(
    const void* __restrict__ xmain, const void* __restrict__ xmod,
    const void* __restrict__ we1, const void* __restrict__ we2,
    const void* __restrict__ wqp, const void* __restrict__ wkp,
    const void* __restrict__ wvp,
    u16* __restrict__ qb, u16* __restrict__ kb, u16* __restrict__ vt)
{
    __shared__ float wf[4608];
    __shared__ int   sflag;
    __shared__ float lh1[64][4][17];
    __shared__ float lh2[64][17];

    const int t = threadIdx.x;
    const int r = t >> 2;
    const int p = t & 3;
    const int row = blockIdx.x * 64 + r;

    if (t == 0) sflag = 0;
    __syncthreads();
    {
        float v = bf2f(((const u16*)xmod)[2 * t]);
        if (fabsf(v) > 16.f) atomicAdd(&sflag, 1);
    }
    __syncthreads();
    const int isf32 = (sflag > 8);

    const float SCL = 0.51006979f;       // (1/sqrt(8)) * log2(e)
    if (isf32) {
        const float* a1 = (const float*)we1; const float* a2 = (const float*)we2;
        const float* aq = (const float*)wqp; const float* ak = (const float*)wkp;
        const float* av = (const float*)wvp;
        for (int i = t; i < 4608; i += 256) {
            if      (i < 3072) wf[i] = a1[i];
            else if (i < 3328) wf[i] = a2[i - 3072];
            else if (i < 3456) wf[i] = aq[i - 3328] * SCL;
            else if (i < 3584) wf[i] = ak[i - 3456];
            else               wf[i] = av[i - 3584];
        }
    } else {
        const u16* a1 = (const u16*)we1; const u16* a2 = (const u16*)we2;
        const u16* aq = (const u16*)wqp; const u16* ak = (const u16*)wkp;
        const u16* av = (const u16*)wvp;
        for (int i = t; i < 4608; i += 256) {
            if      (i < 3072) wf[i] = bf2f(a1[i]);
            else if (i < 3328) wf[i] = bf2f(a2[i - 3072]);
            else if (i < 3456) wf[i] = bf2f(aq[i - 3328]) * SCL;
            else if (i < 3584) wf[i] = bf2f(ak[i - 3456]);
            else               wf[i] = bf2f(av[i - 3584]);
        }
    }
    __syncthreads();

    const float* __restrict__ W1 = wf;
    const float* __restrict__ W2 = wf + 3072;
    const float* __restrict__ Wq = wf + 3328;
    const float* __restrict__ Wk = wf + 3456;
    const float* __restrict__ Wv = wf + 3584;

    float h1p[16];
#pragma unroll
    for (int o = 0; o < 16; ++o) h1p[o] = 0.f;

    if (isf32) {
#pragma unroll
        for (int cc = 0; cc < 12; ++cc) {
            const int c = p + cc * 4;
            float4 xv = (c < 16)
                ? ((const float4*)xmain)[(size_t)row * 16 + c]
                : ((const float4*)xmod)[(size_t)row * 32 + (c - 16)];
            float xs[4] = {xv.x, xv.y, xv.z, xv.w};
#pragma unroll
            for (int j = 0; j < 4; ++j) {
                const float* wr = W1 + (c * 4 + j) * 16;
#pragma unroll
                for (int o = 0; o < 16; ++o) h1p[o] += xs[j] * wr[o];
            }
        }
    } else {
#pragma unroll
        for (int cc = 0; cc < 12; ++cc) {
            const int c = p + cc * 4;
            uint2 xv = (c < 16)
                ? ((const uint2*)xmain)[(size_t)row * 16 + c]
                : ((const uint2*)xmod)[(size_t)row * 32 + (c - 16)];
            float xs[4] = { bf2f((u16)(xv.x & 0xffff)), bf2f((u16)(xv.x >> 16)),
                            bf2f((u16)(xv.y & 0xffff)), bf2f((u16)(xv.y >> 16)) };
#pragma unroll
            for (int j = 0; j < 4; ++j) {
                const float* wr = W1 + (c * 4 + j) * 16;
#pragma unroll
                for (int o = 0; o < 16; ++o) h1p[o] += xs[j] * wr[o];
            }
        }
    }
#pragma unroll
    for (int o = 0; o < 16; ++o) lh1[r][p][o] = h1p[o];
    __syncthreads();

    float h1[16];
#pragma unroll
    for (int o = 0; o < 16; ++o)
        h1[o] = fmaxf(lh1[r][0][o] + lh1[r][1][o] + lh1[r][2][o] + lh1[r][3][o], 0.f);

#pragma unroll
    for (int oo = 0; oo < 4; ++oo) {
        const int o = p * 4 + oo;
        float s = 0.f;
#pragma unroll
        for (int j = 0; j < 16; ++j) s += h1[j] * W2[j * 16 + o];
        lh2[r][o] = fmaxf(s, 0.f);
    }
    __syncthreads();

    float h2[16];
#pragma unroll
    for (int j = 0; j < 16; ++j) h2[j] = lh2[r][j];

    const int tt = row >> 5, kk = row & 31;   // global tile, key-in-tile
    {
        float q0 = 0.f, q1 = 0.f, k0 = 0.f, k1 = 0.f;
        const int o = 2 * p;
#pragma unroll
        for (int j = 0; j < 16; ++j) {
            q0 += h2[j] * Wq[j * 8 + o];
            q1 += h2[j] * Wq[j * 8 + o + 1];
            k0 += h2[j] * Wk[j * 8 + o];
            k1 += h2[j] * Wk[j * 8 + o + 1];
        }
        ((unsigned int*)qb)[(size_t)row * 4 + p] = pk2(q0, q1);
        ((unsigned int*)kb)[(size_t)row * 4 + p] = pk2(k0, k1);
    }

    // V store into per-tile fragment-native layout (4096 B / tile)
    {
        const int b   = kk >> 4, kk4 = kk & 15;
        const int hh  = (kk4 >> 2) & 1;
        const int jj  = (kk4 & 3) + 4 * (kk4 >> 3);
        const size_t cbase = (size_t)tt * 2048 + b * 512 + hh * 256 + jj;
#pragma unroll
        for (int c16 = 0; c16 < 16; ++c16) {
            const int c = p * 16 + c16;
            float v = 0.f;
#pragma unroll
            for (int j = 0; j < 16; ++j) v += h2[j] * Wv[j * 64 + c];
            vt[cbase + (size_t)(c >> 5) * 1024 + (c & 31) * 8] = f2bf(v);
        }
    }
}

// --------------------------- kernel 2: attention partials -------------------
// grid = 96 q-blocks * S=8 = 768 blocks = 3 blocks/CU, one balanced round.
// 4 independent waves / block, ZERO barriers.  V: per-wave-private LDS
// double buffer (2 x 4096B, 4 DMA/tile).  K: register double buffer.
// Dual-S software pipeline; all waits sit >= 1 FIN behind their stage.

__global__ __launch_bounds__(256, 3) void k2_attn(
    const u16* __restrict__ qb, const u16* __restrict__ kb,
    const u16* __restrict__ vt,
    u16* __restrict__ po, float* __restrict__ pl,
    int nsplit, int ntile)
{
    __shared__ char smem[34816];             // 4 waves x 8704 B

    const int tid  = threadIdx.x;
    const int lane = tid & 63;
    const int half = lane >> 5;
    const int l31  = lane & 31;
    const int w    = tid >> 6;               // wave 0..3
    const int qB   = (blockIdx.x % 96) * 128;
    const int sp   = blockIdx.x / 96;
    const int myq  = qB + 32 * w;
    const int tile0 = sp * (NN / nsplit) / 32;

    char* wbase = smem + w * 8704;           // this wave's private region
    uint4* vb0 = (uint4*)wbase;              // V buffer 0 (4096 B)
    uint4* vb1 = vb0 + 256;                  // V buffer 1

    const f32x16 Z = zf16();
    s16x8 qf = zs8();
    if (!half) qf = *(const s16x8*)(qb + (size_t)(myq + l31) * 8);

    s16x8 ones;
#pragma unroll
    for (int i = 0; i < 8; ++i) ones[i] = (short)0x3F80;   // bf16 1.0

    f32x16 acc0 = Z, acc1 = Z, accl = Z;

    // V-stage tile t into LDS buffer: exactly 4 DMA ops (1024B each)
#define STAGE(t, lbase) do {                                                  \
    const char* g_ = (const char*)vt + (size_t)(t) * 4096 + lane * 16;        \
    char* l_ = (char*)(lbase);                                                \
    gld16(g_, l_);                                                            \
    gld16(g_ + 1024, l_ + 1024);                                              \
    gld16(g_ + 2048, l_ + 2048);                                              \
    gld16(g_ + 3072, l_ + 3072);                                              \
} while (0)

    // K fragment load to register (1 vm op; all lanes, l31-dup harmless)
#define KLOAD(t, kr) do {                                                     \
    (kr).q = *(const uint4*)(kb + (size_t)((tile0 + (t)) * 32 + l31) * 8);    \
} while (0)

    // finish one tile from its precomputed S; V frags ds_read just-in-time
#define FIN(S_, lbase) do {                                                   \
    float pr_[16];                                                            \
    _Pragma("unroll")                                                         \
    for (int r_ = 0; r_ < 16; ++r_) pr_[r_] = __builtin_amdgcn_exp2f((S_)[r_]);\
    U8 p0_, p1_;                                                              \
    _Pragma("unroll")                                                         \
    for (int i_ = 0; i_ < 4; ++i_) {                                          \
        p0_.u[i_] = pkbf(pr_[2 * i_],     pr_[2 * i_ + 1]);                   \
        p1_.u[i_] = pkbf(pr_[8 + 2 * i_], pr_[8 + 2 * i_ + 1]);               \
    }                                                                         \
    accl = MFMA_32x32x16_BF16(ones, p0_.v, accl, 0, 0, 0);                    \
    accl = MFMA_32x32x16_BF16(ones, p1_.v, accl, 0, 0, 0);                    \
    QV f_;                                                                    \
    f_.q = *((const uint4*)(lbase) + lane);                                   \
    acc0 = MFMA_32x32x16_BF16(f_.v, p0_.v, acc0, 0, 0, 0);                    \
    f_.q = *((const uint4*)(lbase) + 128 + lane);                             \
    acc1 = MFMA_32x32x16_BF16(f_.v, p0_.v, acc1, 0, 0, 0);                    \
    f_.q = *((const uint4*)(lbase) + 64 + lane);                              \
    acc0 = MFMA_32x32x16_BF16(f_.v, p1_.v, acc0, 0, 0, 0);                    \
    f_.q = *((const uint4*)(lbase) + 192 + lane);                             \
    acc1 = MFMA_32x32x16_BF16(f_.v, p1_.v, acc1, 0, 0, 0);                    \
} while (0)

#define WAIT_VM(n) do {                                                       \
    __builtin_amdgcn_s_waitcnt(WC_VM(n));                                     \
    __builtin_amdgcn_sched_barrier(0);                                        \
} while (0)
#define WAIT_LGKM() do {                                                      \
    __builtin_amdgcn_s_waitcnt(WC_LGKM0);                                     \
    __builtin_amdgcn_sched_barrier(0);                                        \
} while (0)

    QV krA, krB;
    // prologue: K first (so K-waits never drain V-stages), V tiles 0,1
    KLOAD(0, krA);
    KLOAD(1, krB);
    STAGE(tile0 + 0, vb0);
    STAGE(tile0 + 1, vb1);
    f32x16 SA = MFMA_32x32x16_BF16(krA.v, qf, Z, 0, 0, 0);   // S(0)
    f32x16 SB;
    KLOAD(2, krA);
    // queue: KL1, SV0[4], SV1[4], KL2 = 10

    int gt = 0;
    for (; gt + 6 <= ntile; gt += 2) {
        // H1 --- tile gt (vb0); S(gt) in SA, K(gt+1) in krB
        SB = MFMA_32x32x16_BF16(krB.v, qf, Z, 0, 0, 0);      // S(gt+1)
        KLOAD(gt + 3, krB);
        WAIT_VM(6);                  // V(gt) = 7th-oldest: resident
        FIN(SA, vb0);
        WAIT_LGKM();
        STAGE(tile0 + gt + 2, vb0);
        // H2 --- tile gt+1 (vb1); K(gt+2) in krA
        SA = MFMA_32x32x16_BF16(krA.v, qf, Z, 0, 0, 0);      // S(gt+2)
        WAIT_VM(6);                  // V(gt+1) = 7th-oldest: resident
        FIN(SB, vb1);
        WAIT_LGKM();
        STAGE(tile0 + gt + 3, vb1);
        KLOAD(gt + 4, krA);
    }
    // peeled pair A: tiles ntile-4, ntile-3 (gt == ntile-4)
    SB = MFMA_32x32x16_BF16(krB.v, qf, Z, 0, 0, 0);          // S(ntile-3)
    KLOAD(gt + 3, krB);                                      // K(ntile-1)
    WAIT_VM(6);
    FIN(SA, vb0);
    WAIT_LGKM();
    STAGE(tile0 + gt + 2, vb0);                              // V(ntile-2)
    SA = MFMA_32x32x16_BF16(krA.v, qf, Z, 0, 0, 0);          // S(ntile-2)
    WAIT_VM(6);
    FIN(SB, vb1);
    WAIT_LGKM();
    STAGE(tile0 + gt + 3, vb1);                              // V(ntile-1)
    // peeled pair B: tiles ntile-2, ntile-1
    SB = MFMA_32x32x16_BF16(krB.v, qf, Z, 0, 0, 0);          // S(ntile-1)
    WAIT_VM(4);                      // V(ntile-2): 4 newer (SV ntile-1)
    FIN(SA, vb0);
    WAIT_VM(0);                      // V(ntile-1)
    FIN(SB, vb1);

#undef STAGE
#undef KLOAD
#undef FIN
#undef WAIT_VM
#undef WAIT_LGKM

    // denominator: all accl rows identical = full 64-lane key-sum per query
    const float ls = accl[0];

    // ---- epilogue: per-wave PRIVATE transpose scratch (aliases V bufs) ----
    __builtin_amdgcn_s_waitcnt(WC_LGKM0);    // last FIN's ds_reads retired
    __builtin_amdgcn_sched_barrier(0);
    float* sfw = (float*)wbase;              // 8704 B >= 2144 floats
#pragma unroll
    for (int r = 0; r < 16; ++r) {
        const int c = (r & 3) + 8 * (r >> 2) + 4 * half;
        sfw[c * 33 + l31]        = acc0[r];
        sfw[(32 + c) * 33 + l31] = acc1[r];
    }
    if (lane < 32) sfw[2112 + l31] = ls;

    u16* poS = po + (size_t)sp * (NN * 64);
    const int lq  = lane >> 1;               // query 0..31 within wave
    const int cb0 = (lane & 1) * 32;         // channel base 0 or 32
    unsigned int u[16];
#pragma unroll
    for (int i = 0; i < 16; ++i)
        u[i] = pkbf(sfw[(cb0 + 2 * i) * 33 + lq],
                    sfw[(cb0 + 2 * i + 1) * 33 + lq]);
    u16* dst = poS + (size_t)(myq + lq) * 64 + cb0;
    *(uint4*)(dst)      = make_uint4(u[0],  u[1],  u[2],  u[3]);
    *(uint4*)(dst + 8)  = make_uint4(u[4],  u[5],  u[6],  u[7]);
    *(uint4*)(dst + 16) = make_uint4(u[8],  u[9],  u[10], u[11]);
    *(uint4*)(dst + 24) = make_uint4(u[12], u[13], u[14], u[15]);
    if (lane < 32)
        pl[(size_t)sp * NN + myq + l31] = sfw[2112 + l31];
}

// --------------------------- kernel 3: reduce splits + normalize ------------
__global__ __launch_bounds__(256) void k3_norm(
    const u16* __restrict__ po, const float* __restrict__ pl,
    float4* __restrict__ out, int nsplit)
{
    const int i = blockIdx.x * 256 + threadIdx.x;   // 196608 float4 outputs
    const int row = i >> 4;
    const int c0 = (i & 15) * 4;
    float l = 0.f;
    float o0 = 0.f, o1 = 0.f, o2 = 0.f, o3 = 0.f;
    for (int s = 0; s < nsplit; ++s) {
        l += pl[(size_t)s * NN + row];
        uint2 p = *(const uint2*)(po + (size_t)s * (NN * 64) +
                                  (size_t)row * 64 + c0);
        o0 += bf2f((u16)(p.x & 0xffff)); o1 += bf2f((u16)(p.x >> 16));
        o2 += bf2f((u16)(p.y & 0xffff)); o3 += bf2f((u16)(p.y >> 16));
    }
    const float rl = 1.0f / l;
    out[i] = make_float4(o0 * rl, o1 * rl, o2 * rl, o3 * rl);
}

// ---------------------------------------------------------------------------
extern "C" void kernel_launch(void* const* d_in, const int* in_sizes, int n_in,
                              void* d_out, int out_size, void* d_ws, size_t ws_size,
                              hipStream_t stream)
{
    const void* xmain = d_in[0];
    const void* xmod  = d_in[1];
    // d_in[2] = xyz (unused by the reference)
    const void* we1   = d_in[3];
    const void* we2   = d_in[4];
    const void* wq    = d_in[5];
    const void* wk    = d_in[6];
    const void* wv    = d_in[7];

    char* ws = (char*)d_ws;
    u16*   qb   = (u16*)  (ws + OFF_QB);
    u16*   kb   = (u16*)  (ws + OFF_KB);
    u16*   vt   = (u16*)  (ws + OFF_VT);

    // S = 8: grid 768 = 3 blocks/CU, one balanced round, minimal partials.
    int S = 8;
    while (S > 1) {
        size_t need = (size_t)OFF_PO + (size_t)S * (NN * 64 * 2) +
                      (size_t)S * (NN * 4);
        if (ws_size >= need) break;
        S >>= 1;
    }
    u16*   po = (u16*)(ws + OFF_PO);
    float* pl = (float*)(ws + OFF_PO + (size_t)S * (NN * 64 * 2));
    const int ntile = NN / (32 * S);

    k1_qkv<<<192, 256, 0, stream>>>(xmain, xmod, we1, we2, wq, wk, wv,
                                    qb, kb, vt);
    k2_attn<<<96 * S, 256, 0, stream>>>(qb, kb, vt, po, pl, S, ntile);
    k3_norm<<<768, 256, 0, stream>>>(po, pl, (float4*)d_out, S);
}